// Round 7
// baseline (626.355 us; speedup 1.0000x reference)
//
#include <hip/hip_runtime.h>

// ---------------------------------------------------------------------------
// StandAttention: out = softmax_causal((xWq+bq)(xWk+bk)^T / sqrt(d)) (xWv+bv) Wo + bo
// b=4, s=4096, d=1024. fp32 in/out, bf16 MFMA compute.
//
// R7 changes vs R6 (R6: 512 us; proj = 840 TF = m97-structure plateau; per-CU
// LDS-read pipe (~1150 cyc/window) as loaded as MFMA pipe (~1240) -> density fix):
//  - 128x256 macro-tile, 4 waves of 64x128 (acc 4x8): LDS reads/MFMA -25%,
//    staged bytes/FLOP -33%, barriers/FLOP halved. 96KB LDS dbuf -> 1 block/CU,
//    grid 256. vmcnt(12) cross-barrier prefetch (12 loads/wave/stage).
//  - maps: proj groups all 12 tiles (3 mats x 4 n) of an A row-block on one XCD
//    consecutively; scores = exact 136-tile per-XCD range (tail: 64 blocks x 1
//    extra tile); PV keeps perfect 66-iter balance; outproj 2 uniform slots.
// ---------------------------------------------------------------------------

typedef unsigned short u16;
typedef __attribute__((ext_vector_type(4))) unsigned short u16x4;
typedef __attribute__((ext_vector_type(8))) unsigned short u16x8;
typedef __attribute__((ext_vector_type(8))) __bf16 bf16x8;
typedef __attribute__((ext_vector_type(4))) float f32x4;

typedef const __attribute__((address_space(1))) void* as1cp;
typedef __attribute__((address_space(3))) void* as3p;

struct GemmPtrs {
  const u16* A[4];
  const u16* B[4];
  const float* bias[4];
  void* C[4];
};
struct TransPtrs {
  const void* in[4];
  u16* out[4];
};
struct SmPtrs {
  u16* P[4];
};

__device__ __forceinline__ u16 f2bf(float f) {
  union { float f; unsigned int i; } c; c.f = f;
  unsigned int r = c.i + 0x7fffu + ((c.i >> 16) & 1u);   // RNE
  return (u16)(r >> 16);
}
__device__ __forceinline__ float bf2f(u16 u) {
  union { unsigned int i; float f; } c; c.i = ((unsigned int)u) << 16;
  return c.f;
}

// ---------------- cast fp32 -> bf16 (vectorized) ----------------
__global__ __launch_bounds__(256) void cast_f32_bf16(const float* __restrict__ in,
                                                     u16* __restrict__ out, int n4) {
  int i = blockIdx.x * blockDim.x + threadIdx.x;
  if (i >= n4) return;
  float4 v = ((const float4*)in)[i];
  u16x4 u;
  u.x = f2bf(v.x); u.y = f2bf(v.y); u.z = f2bf(v.z); u.w = f2bf(v.w);
  ((u16x4*)out)[i] = u;
}

// ---------------- LDS-tiled transpose (-> bf16), batched by z ----------------
template <bool IN_F32>
__global__ __launch_bounds__(256) void transpose_to_bf16(TransPtrs tp, int R, int C) {
  __shared__ u16 t[32][34];
  int z = blockIdx.z;
  int tx = threadIdx.x, ty = threadIdx.y;
  int c0 = blockIdx.x * 32, r0 = blockIdx.y * 32;
#pragma unroll
  for (int dy = 0; dy < 4; ++dy) {
    int r = r0 + ty + dy * 8;
    int c = c0 + tx;
    u16 hv;
    if (IN_F32) hv = f2bf(((const float*)tp.in[z])[(size_t)r * C + c]);
    else        hv = ((const u16*)tp.in[z])[(size_t)r * C + c];
    t[ty + dy * 8][tx] = hv;
  }
  __syncthreads();
  u16* op = tp.out[z];
#pragma unroll
  for (int dy = 0; dy < 4; ++dy) {
    int a = ty + dy * 8;
    op[(size_t)(c0 + a) * R + r0 + tx] = t[tx][a];
  }
}

// ---------------- causal softmax, in-place, trimmed to j<=row ----------------
__global__ __launch_bounds__(256) void softmax_causal(SmPtrs sp) {
  int row = blockIdx.x;
  u16* P = sp.P[blockIdx.y];
  int tid = threadIdx.x;
  int lane = tid & 63, wv = tid >> 6;
  u16x8* prow = (u16x8*)(P + (size_t)row * 4096);
  int nch = (row >> 3) + 1;           // vec8 chunks containing any j<=row
  int fend = ((row >> 7) + 1) << 4;   // chunks to the 128 boundary PV reads
  int c0 = tid, c1 = tid + 256;
  bool a0 = c0 < nch, a1 = c1 < nch;
  float vals[16];
  float lmax = -3.0e38f;
  if (a0) {
    u16x8 u = prow[c0];
#pragma unroll
    for (int e = 0; e < 8; ++e) {
      float f = (c0 * 8 + e <= row) ? bf2f(u[e]) : -3.0e38f;
      vals[e] = f; lmax = fmaxf(lmax, f);
    }
  } else {
#pragma unroll
    for (int e = 0; e < 8; ++e) vals[e] = -3.0e38f;
  }
  if (a1) {
    u16x8 u = prow[c1];
#pragma unroll
    for (int e = 0; e < 8; ++e) {
      float f = (c1 * 8 + e <= row) ? bf2f(u[e]) : -3.0e38f;
      vals[8 + e] = f; lmax = fmaxf(lmax, f);
    }
  } else {
#pragma unroll
    for (int e = 0; e < 8; ++e) vals[8 + e] = -3.0e38f;
  }
  __shared__ float red[8];
#pragma unroll
  for (int off = 32; off > 0; off >>= 1) lmax = fmaxf(lmax, __shfl_down(lmax, off, 64));
  if (lane == 0) red[wv] = lmax;
  __syncthreads();
  float m2 = fmaxf(fmaxf(red[0], red[1]), fmaxf(red[2], red[3]));
  float lsum = 0.f;
#pragma unroll
  for (int e = 0; e < 16; ++e) {
    float ev = __expf(vals[e] - m2);
    vals[e] = ev;
    lsum += ev;
  }
#pragma unroll
  for (int off = 32; off > 0; off >>= 1) lsum += __shfl_down(lsum, off, 64);
  if (lane == 0) red[4 + wv] = lsum;
  __syncthreads();
  float inv = 1.0f / (red[4] + red[5] + red[6] + red[7]);
  if (a0) {
    u16x8 u;
#pragma unroll
    for (int e = 0; e < 8; ++e) u[e] = f2bf(vals[e] * inv);
    prow[c0] = u;
  }
  if (a1) {
    u16x8 u;
#pragma unroll
    for (int e = 0; e < 8; ++e) u[e] = f2bf(vals[8 + e] * inv);
    prow[c1] = u;
  }
  u16x8 zz = (u16x8)(u16)0;
  for (int c = nch + tid; c < fend; c += 256) prow[c] = zz;
}

// ---------------- persistent MFMA GEMM: C[M,N] = A[M,K] @ Bt[N,K]^T ----------------
// 128x256 macro-tile, BK=64, 4 waves of 64x128 (acc 4x8), 96KB dbuf LDS,
// cross-barrier prefetch vmcnt(12), XOR bank swizzle, XCD-aware maps, grid 256.
// MODE 0: q/k/v projections (6 slots)   MODE 1: causal scores (5|4 slots)
// MODE 2: PV (2 slots, 66 iters/block)  MODE 3: out-projection (2 slots)
template <int MODE, bool OUT_BF16, bool HAS_BIAS, int MAXSLOT, int KDIM, int LDB>
__global__ __launch_bounds__(256, 1) void gemm_persist(GemmPtrs p, int N, float cscale) {
  __shared__ __align__(16) u16 As[2][128 * 64];
  __shared__ __align__(16) u16 Bs[2][256 * 64];
  int b = blockIdx.x;
  int x = b & 7, q = b >> 3;                  // x = XCD, q = index on XCD [0,32)
  int tid = threadIdx.x, lane = tid & 63, wv = tid >> 6;
  int wm = (wv >> 1) * 64, wn = (wv & 1) * 128;
  int lrow = lane & 15, lquad = lane >> 4;
  int srow = lane >> 3, scol = ((lane & 7) ^ srow) * 8;

  struct TP { const u16* A; const u16* B; int niter, tm, tn, z; };
  auto tileOf = [&](int s) {
    TP t;
    if (MODE == 0) {
      int idx = s * 32 + q;                   // [0,192) per XCD
      int ml = idx / 12, r = idx - ml * 12;   // 12 tiles (3 mat x 4 n) per A-block
      t.z = r >> 2;
      t.tm = (ml * 8 + x) << 7; t.tn = (r & 3) << 8; t.niter = KDIM >> 6;
    } else if (MODE == 1) {
      int T = x * 136 + s * 32 + q;           // exact per-XCD range [0,1088)
      t.z = T / 272; int L = T - t.z * 272;
      // invert cum(m) = (m^2+2m+(m&1))/4 (tiles per batch, BN=256 causal)
      int m = (int)(2.f * __fsqrt_rn((float)L + 1.f)) - 1;
      if (m < 0) m = 0;
      while ((( (m+1)*(m+1) + 2*(m+1) + ((m+1)&1) ) >> 2) <= L) ++m;
      while ((( m*m + 2*m + (m&1) ) >> 2) > L) --m;
      t.tm = m << 7; t.tn = (L - ((m*m + 2*m + (m&1)) >> 2)) << 8;
      t.niter = KDIM >> 6;
    } else if (MODE == 2) {
      int w = q & 7, h = w >> 2;
      int i = (s == 0) ? (h ? 15 - x : x) : (h ? 16 + x : 31 - x);
      t.z = q >> 3; t.tm = i << 7; t.tn = (w & 3) << 8; t.niter = (i + 1) * 2;
    } else {
      int idx = s * 32 + q;                   // [0,64) per XCD
      t.z = 0; t.tm = ((idx >> 2) * 8 + x) << 7; t.tn = (idx & 3) << 8;
      t.niter = KDIM >> 6;
    }
    t.A = p.A[t.z] + (size_t)t.tm * KDIM;
    t.B = p.B[t.z] + (size_t)t.tn * LDB;
    return t;
  };
  int nslot = (MODE == 1) ? (q < 8 ? 5 : 4) : MAXSLOT;
  int total = (MODE == 2) ? 66 : nslot * (KDIM >> 6);   // even: 96/80/64/66/32

  // per-lane element offsets for staging (A: 4 chunks, B: 8 chunks per wave)
  int aoff = (wv * 32 + srow) * KDIM + scol;
  int boff = (wv * 64 + srow) * LDB + scol;

  TP st = tileOf(0);
  int stk = 0, sslot = 0;
  const u16* gA = st.A + aoff;
  const u16* gB = st.B + boff;

  auto stageTo = [&](int sb) {
#pragma unroll
    for (int tt = 0; tt < 4; ++tt)
      __builtin_amdgcn_global_load_lds((as1cp)(gA + tt * 8 * KDIM),
                                       (as3p)&As[sb][(wv * 4 + tt) * 512], 16, 0, 0);
#pragma unroll
    for (int tt = 0; tt < 8; ++tt)
      __builtin_amdgcn_global_load_lds((as1cp)(gB + tt * 8 * LDB),
                                       (as3p)&Bs[sb][(wv * 8 + tt) * 512], 16, 0, 0);
  };
  auto adv = [&]() {
    gA += 64; gB += 64;
    if (++stk == st.niter) {
      stk = 0;
      if (++sslot < nslot) {
        st = tileOf(sslot);
        gA = st.A + aoff;
        gB = st.B + boff;
      }
    }
  };

  f32x4 acc[4][8];
#pragma unroll
  for (int i = 0; i < 4; ++i)
#pragma unroll
    for (int j = 0; j < 8; ++j) acc[i][j] = (f32x4){0.f, 0.f, 0.f, 0.f};

  auto compute = [&](int cb) __attribute__((always_inline)) {
#pragma unroll
    for (int ks = 0; ks < 64; ks += 32) {
      bf16x8 af[4], bg[8];
#pragma unroll
      for (int mt = 0; mt < 4; ++mt) {
        int r = wm + mt * 16 + lrow;
        int jb = (ks >> 3) + lquad;
        af[mt] = *(const bf16x8*)&As[cb][r * 64 + ((jb ^ (r & 7)) << 3)];
      }
#pragma unroll
      for (int nt = 0; nt < 8; ++nt) {
        int r = wn + nt * 16 + lrow;
        int jb = (ks >> 3) + lquad;
        bg[nt] = *(const bf16x8*)&Bs[cb][r * 64 + ((jb ^ (r & 7)) << 3)];
      }
#pragma unroll
      for (int mt = 0; mt < 4; ++mt)
#pragma unroll
        for (int nt = 0; nt < 8; ++nt)
          acc[mt][nt] = __builtin_amdgcn_mfma_f32_16x16x32_bf16(af[mt], bg[nt], acc[mt][nt], 0, 0, 0);
    }
  };

  TP ct = st;
  int cit = 0, cslot = 0;
  auto epi = [&]() {
    if (++cit == ct.niter) {
      const float* bias = HAS_BIAS ? p.bias[ct.z] : nullptr;
#pragma unroll
      for (int mt = 0; mt < 4; ++mt) {
#pragma unroll
        for (int reg = 0; reg < 4; ++reg) {
          int r = ct.tm + wm + mt * 16 + lquad * 4 + reg;
#pragma unroll
          for (int nt = 0; nt < 8; ++nt) {
            int cidx = ct.tn + wn + nt * 16 + lrow;
            float vvv = acc[mt][nt][reg] * cscale;
            if (HAS_BIAS) vvv += bias[cidx];
            if (OUT_BF16) ((u16*)p.C[ct.z])[(size_t)r * N + cidx] = f2bf(vvv);
            else          ((float*)p.C[ct.z])[(size_t)r * N + cidx] = vvv;
          }
        }
      }
#pragma unroll
      for (int i = 0; i < 4; ++i)
#pragma unroll
        for (int j = 0; j < 8; ++j) acc[i][j] = (f32x4){0.f, 0.f, 0.f, 0.f};
      cit = 0;
      if (++cslot < nslot) ct = tileOf(cslot);
    }
  };

  stageTo(0);
  adv();
  for (int it = 0; it < total; it += 2) {
    // ---- buffer 0 ----
    if (it + 1 < total) {
      stageTo(1);
      adv();
      asm volatile("s_waitcnt vmcnt(12)" ::: "memory");  // buf-0 loads landed
    } else {
      asm volatile("s_waitcnt vmcnt(0)" ::: "memory");
    }
    asm volatile("s_barrier" ::: "memory");
    compute(0);
    asm volatile("s_barrier" ::: "memory");
    epi();
    // ---- buffer 1 ----
    if (it + 2 < total) {
      stageTo(0);
      adv();
      asm volatile("s_waitcnt vmcnt(12)" ::: "memory");  // buf-1 loads landed
    } else {
      asm volatile("s_waitcnt vmcnt(0)" ::: "memory");
    }
    asm volatile("s_barrier" ::: "memory");
    compute(1);
    asm volatile("s_barrier" ::: "memory");
    epi();
  }
}

// ---------------------------------------------------------------------------
extern "C" void kernel_launch(void* const* d_in, const int* in_sizes, int n_in,
                              void* d_out, int out_size, void* d_ws, size_t ws_size,
                              hipStream_t stream) {
  const float* x  = (const float*)d_in[0];
  const float* Wq = (const float*)d_in[1];
  const float* bq = (const float*)d_in[2];
  const float* Wk = (const float*)d_in[3];
  const float* bk = (const float*)d_in[4];
  const float* Wv = (const float*)d_in[5];
  const float* bv = (const float*)d_in[6];
  const float* Wo = (const float*)d_in[7];
  const float* bo = (const float*)d_in[8];

  const int S = 4096, D = 1024;
  const size_t XE = (size_t)4 * S * D;
  const size_t BSE = (size_t)S * D;

  char* ws = (char*)d_ws;
  u16* xb  = (u16*)(ws + 0);                     // [16384,1024]; dead after proj -> vT
  u16* q   = (u16*)(ws + 33554432);
  u16* k   = (u16*)(ws + 67108864);
  u16* v   = (u16*)(ws + 100663296);             // dead after transpose -> attn3
  u16* ctx = (u16*)(ws + 134217728);
  u16* wqT = (u16*)(ws + 167772160);
  u16* wkT = wqT + 1048576;
  u16* wvT = wkT + 1048576;
  u16* woT = wvT + 1048576;
  u16* attn2 = (u16*)(ws + 176160768);           // [4096,4096] bf16
  u16* attn0 = (u16*)d_out;                      // d_out 67MB, dead until out-proj
  u16* attn1 = attn0 + (size_t)S * S;
  u16* attn3 = v;
  u16* vT = xb;                                  // [1024,4096] per batch, contiguous
  u16* attn[4] = {attn0, attn1, attn2, attn3};

  // 1. cast x -> bf16
  cast_f32_bf16<<<(int)(XE / 4 / 256), 256, 0, stream>>>(x, xb, (int)(XE / 4));
  // 2. weight transposes
  {
    TransPtrs tp = {{Wq, Wk, Wv, Wo}, {wqT, wkT, wvT, woT}};
    transpose_to_bf16<true><<<dim3(32, 32, 4), dim3(32, 8), 0, stream>>>(tp, D, D);
  }
  // 3. q/k/v projections (1536 tiles over 256 blocks, 6 slots)
  {
    GemmPtrs gp = {{xb, xb, xb, xb}, {wqT, wkT, wvT, wqT},
                   {bq, bk, bv, bq}, {q, k, v, q}};
    gemm_persist<0, true, true, 6, 1024, 1024><<<256, 256, 0, stream>>>(gp, D, 1.0f);
  }
  // 4. v -> v^T per batch (overwrites dead xb)
  {
    TransPtrs tp = {{v, v + BSE, v + 2 * BSE, v + 3 * BSE},
                    {vT, vT + BSE, vT + 2 * BSE, vT + 3 * BSE}};
    transpose_to_bf16<false><<<dim3(D / 32, S / 32, 4), dim3(32, 8), 0, stream>>>(tp, S, D);
  }
  // 5. scores = (q k^T)*scale -> bf16 attn_z (1088 causal tiles over 256 blocks)
  {
    GemmPtrs gp = {{q, q + BSE, q + 2 * BSE, q + 3 * BSE},
                   {k, k + BSE, k + 2 * BSE, k + 3 * BSE},
                   {nullptr, nullptr, nullptr, nullptr},
                   {attn[0], attn[1], attn[2], attn[3]}};
    gemm_persist<1, true, false, 5, 1024, 1024><<<256, 256, 0, stream>>>(gp, S, 0.03125f);
  }
  // 6. causal softmax in-place (trimmed + fringe zeros)
  {
    SmPtrs sp = {{attn[0], attn[1], attn[2], attn[3]}};
    softmax_causal<<<dim3(S, 4), 256, 0, stream>>>(sp);
  }
  // 7. ctx = attn @ v (512 tiles; XCD-local i-sets, 66 iters per block)
  {
    GemmPtrs gp = {{attn[0], attn[1], attn[2], attn[3]},
                   {vT, vT + BSE, vT + 2 * BSE, vT + 3 * BSE},
                   {nullptr, nullptr, nullptr, nullptr},
                   {ctx, ctx + BSE, ctx + 2 * BSE, ctx + 3 * BSE}};
    gemm_persist<2, true, false, 2, 4096, 4096><<<256, 256, 0, stream>>>(gp, D, 1.0f);
  }
  // 8. out = ctx Wo^T + bo (fp32 -> d_out, overwrites dead attn0/1)
  {
    GemmPtrs gp = {{ctx, ctx, ctx, ctx}, {woT, woT, woT, woT},
                   {bo, bo, bo, bo}, {d_out, d_out, d_out, d_out}};
    gemm_persist<3, false, true, 2, 1024, 1024><<<256, 256, 0, stream>>>(gp, D, 1.0f);
  }
}